// Round 2
// baseline (1840.265 us; speedup 1.0000x reference)
//
#include <hip/hip_runtime.h>
#include <stdint.h>
#include <math.h>

#define N_TOK 4096
#define H_DIM 4096
#define V_DIM 32000
#define BM 128
#define BN 128
#define BK 64
#define CT_NUM (V_DIM / BN)   // 250 column tiles
#define MT_NUM (N_TOK / BM)   // 32 row tiles

typedef __attribute__((ext_vector_type(8))) short short8;
typedef __attribute__((ext_vector_type(4))) float f32x4;

__device__ __forceinline__ unsigned short f2bf(float x) {
  union { float f; unsigned int u; } v; v.f = x;
  unsigned int r = v.u + 0x7fffu + ((v.u >> 16) & 1u);
  return (unsigned short)(r >> 16);
}

__device__ __forceinline__ void async16(const unsigned short* g, void* lds) {
  __builtin_amdgcn_global_load_lds(
      (const __attribute__((address_space(1))) void*)g,
      (__attribute__((address_space(3))) void*)lds, 16, 0, 0);
}

__global__ __launch_bounds__(256) void cast_f32_to_bf16(
    const float* __restrict__ in, unsigned short* __restrict__ out, int n4) {
  int stride = gridDim.x * blockDim.x;
  for (int idx = blockIdx.x * blockDim.x + threadIdx.x; idx < n4; idx += stride) {
    float4 v = ((const float4*)in)[idx];
    ushort4 o;
    o.x = f2bf(v.x); o.y = f2bf(v.y); o.z = f2bf(v.z); o.w = f2bf(v.w);
    ((ushort4*)out)[idx] = o;
  }
}

// logits[m][v] = sum_k X[m][k] * W[v][k]; writes per-(row, coltile) online
// softmax partials: pmax/psum laid out [coltile][row].
// MODE 0: inputs pre-cast to bf16, global_load_lds staging.
// MODE 1: fp32 inputs, convert-on-the-fly reg staging (ws too small fallback).
template<int MODE>
__global__ __launch_bounds__(256) void gemm_lse(
    const unsigned short* __restrict__ Xb, const unsigned short* __restrict__ Wb,
    const float* __restrict__ Xf, const float* __restrict__ Wf,
    float* __restrict__ pmax, float* __restrict__ psum) {
  __shared__ unsigned short As[BM * BK];   // 16 KB, row-major [row][k]
  __shared__ unsigned short Bs[BN * BK];   // 16 KB

  const int ct = blockIdx.x / MT_NUM;   // m-tile fastest: W panel reused via L2/LLC
  const int mt = blockIdx.x % MT_NUM;
  const int mbase = mt * BM;
  const int cbase = ct * BN;

  const int tid = threadIdx.x;
  const int lane = tid & 63;
  const int wid = tid >> 6;
  const int wr = wid >> 1;   // wave's 64-row band
  const int wc = wid & 1;    // wave's 64-col band

  f32x4 acc[4][4];
#pragma unroll
  for (int i = 0; i < 4; i++)
#pragma unroll
    for (int j = 0; j < 4; j++) { f32x4 z = {0.f, 0.f, 0.f, 0.f}; acc[i][j] = z; }

  for (int ks = 0; ks < H_DIM / BK; ks++) {
    const int k0 = ks * BK;
    if (MODE == 0) {
#pragma unroll
      for (int r = 0; r < 4; r++) {
        // LDS dest is wave-uniform base; HW adds lane*16. Source must match
        // the element that belongs at byte offset o = base + lane*16.
        int o = r * 4096 + wid * 1024 + lane * 16;
        int row = o >> 7;               // 128 B per LDS row (BK*2)
        int kc = (o & 127) >> 1;        // bf16 column within row
        async16(Xb + (size_t)(mbase + row) * H_DIM + k0 + kc,
                (char*)As + r * 4096 + wid * 1024);
        async16(Wb + (size_t)(cbase + row) * H_DIM + k0 + kc,
                (char*)Bs + r * 4096 + wid * 1024);
      }
    } else {
#pragma unroll
      for (int r = 0; r < 4; r++) {
        int o = r * 4096 + wid * 1024 + lane * 16;
        int row = o >> 7;
        int kc = (o & 127) >> 1;
        const float* xs = Xf + (size_t)(mbase + row) * H_DIM + k0 + kc;
        const float* wv = Wf + (size_t)(cbase + row) * H_DIM + k0 + kc;
        float4 x0 = *(const float4*)xs, x1 = *(const float4*)(xs + 4);
        float4 w0 = *(const float4*)wv, w1 = *(const float4*)(wv + 4);
        short8 xa, wa;
        xa[0] = f2bf(x0.x); xa[1] = f2bf(x0.y); xa[2] = f2bf(x0.z); xa[3] = f2bf(x0.w);
        xa[4] = f2bf(x1.x); xa[5] = f2bf(x1.y); xa[6] = f2bf(x1.z); xa[7] = f2bf(x1.w);
        wa[0] = f2bf(w0.x); wa[1] = f2bf(w0.y); wa[2] = f2bf(w0.z); wa[3] = f2bf(w0.w);
        wa[4] = f2bf(w1.x); wa[5] = f2bf(w1.y); wa[6] = f2bf(w1.z); wa[7] = f2bf(w1.w);
        *(short8*)((char*)As + o) = xa;
        *(short8*)((char*)Bs + o) = wa;
      }
    }
    __syncthreads();
#pragma unroll
    for (int kk = 0; kk < 2; kk++) {
      short8 a[4], b[4];
#pragma unroll
      for (int m = 0; m < 4; m++) {
        int off = (wr * 64 + m * 16 + (lane & 15)) * (BK * 2) + kk * 64 + (lane >> 4) * 16;
        a[m] = *(const short8*)((const char*)As + off);
      }
#pragma unroll
      for (int n = 0; n < 4; n++) {
        int off = (wc * 64 + n * 16 + (lane & 15)) * (BK * 2) + kk * 64 + (lane >> 4) * 16;
        b[n] = *(const short8*)((const char*)Bs + off);
      }
#pragma unroll
      for (int m = 0; m < 4; m++)
#pragma unroll
        for (int n = 0; n < 4; n++)
          acc[m][n] = __builtin_amdgcn_mfma_f32_16x16x32_bf16(a[m], b[n], acc[m][n], 0, 0, 0);
    }
    __syncthreads();
  }

  // Epilogue: per-row (max, sum exp) over this block's 128 columns.
  // C/D map: col = lane&15 (within frag n), row = (lane>>4)*4 + q (within frag m).
  float* red = (float*)As;   // [128 rows][wc][2]
  const int g = lane >> 4;
#pragma unroll
  for (int m = 0; m < 4; m++) {
#pragma unroll
    for (int q = 0; q < 4; q++) {
      float v0 = acc[m][0][q], v1 = acc[m][1][q], v2 = acc[m][2][q], v3 = acc[m][3][q];
      float mx = fmaxf(fmaxf(v0, v1), fmaxf(v2, v3));
#pragma unroll
      for (int d = 1; d < 16; d <<= 1) mx = fmaxf(mx, __shfl_xor(mx, d));
      float se = __expf(v0 - mx) + __expf(v1 - mx) + __expf(v2 - mx) + __expf(v3 - mx);
#pragma unroll
      for (int d = 1; d < 16; d <<= 1) se += __shfl_xor(se, d);
      if ((lane & 15) == 0) {
        int row = wr * 64 + m * 16 + g * 4 + q;
        red[row * 4 + wc * 2 + 0] = mx;
        red[row * 4 + wc * 2 + 1] = se;
      }
    }
  }
  __syncthreads();
  if (tid < BM) {
    float m0 = red[tid * 4 + 0], s0 = red[tid * 4 + 1];
    float m1 = red[tid * 4 + 2], s1 = red[tid * 4 + 3];
    float M = fmaxf(m0, m1);
    float S = s0 * __expf(m0 - M) + s1 * __expf(m1 - M);
    size_t o = (size_t)ct * N_TOK + mbase + tid;
    pmax[o] = M;
    psum[o] = S;
  }
}

// Exact fp32 target logit: tl[n] = dot(x[n,:], W[y[n],:]).
__global__ __launch_bounds__(256) void target_logit(
    const float* __restrict__ X, const float* __restrict__ W,
    const int* __restrict__ y, float* __restrict__ tl) {
  __shared__ float red[4];
  int row = blockIdx.x;
  int lab = y[row];
  float s = 0.f;
  if (lab >= 0 && lab < V_DIM) {
    const float4* xr = (const float4*)(X + (size_t)row * H_DIM);
    const float4* wr = (const float4*)(W + (size_t)lab * H_DIM);
    for (int i = threadIdx.x; i < H_DIM / 4; i += 256) {
      float4 a = xr[i], b = wr[i];
      s += a.x * b.x + a.y * b.y + a.z * b.z + a.w * b.w;
    }
  }
#pragma unroll
  for (int o = 32; o > 0; o >>= 1) s += __shfl_down(s, o);
  if ((threadIdx.x & 63) == 0) red[threadIdx.x >> 6] = s;
  __syncthreads();
  if (threadIdx.x == 0) tl[row] = red[0] + red[1] + red[2] + red[3];
}

__global__ __launch_bounds__(256) void combine_rows(
    const float* __restrict__ pmax, const float* __restrict__ psum,
    const float* __restrict__ tl, const int* __restrict__ y,
    float* __restrict__ lossb, float* __restrict__ validb) {
  int row = blockIdx.x * 256 + threadIdx.x;
  if (row >= N_TOK) return;
  float M = -INFINITY, S = 0.f;
  for (int ct = 0; ct < CT_NUM; ct++) {
    float m = pmax[(size_t)ct * N_TOK + row];
    float s = psum[(size_t)ct * N_TOK + row];
    float Mn = fmaxf(M, m);
    S = S * __expf(M - Mn) + s * __expf(m - Mn);
    M = Mn;
  }
  bool valid = (y[row] != -100);   // IGNORE_INDEX
  lossb[row] = valid ? (M + __logf(S) - tl[row]) : 0.f;
  validb[row] = valid ? 1.f : 0.f;
}

__global__ __launch_bounds__(256) void finalize_loss(
    const float* __restrict__ lossb, const float* __restrict__ validb,
    float* __restrict__ out) {
  __shared__ float rs[4], rc[4];
  float s = 0.f, c = 0.f;
  for (int i = threadIdx.x; i < N_TOK; i += 256) { s += lossb[i]; c += validb[i]; }
#pragma unroll
  for (int o = 32; o > 0; o >>= 1) { s += __shfl_down(s, o); c += __shfl_down(c, o); }
  if ((threadIdx.x & 63) == 0) { rs[threadIdx.x >> 6] = s; rc[threadIdx.x >> 6] = c; }
  __syncthreads();
  if (threadIdx.x == 0) {
    float S = rs[0] + rs[1] + rs[2] + rs[3];
    float C = rc[0] + rc[1] + rc[2] + rc[3];
    out[0] = S / fmaxf(C, 1.f);
  }
}

extern "C" void kernel_launch(void* const* d_in, const int* in_sizes, int n_in,
                              void* d_out, int out_size, void* d_ws, size_t ws_size,
                              hipStream_t stream) {
  const float* x = (const float*)d_in[0];
  const int* y = (const int*)d_in[1];      // harness delivers integers as int32
  const float* W = (const float*)d_in[2];
  float* out = (float*)d_out;
  char* ws = (char*)d_ws;

  const size_t szWb = (size_t)V_DIM * H_DIM * 2;      // 262,144,000
  const size_t szXb = (size_t)N_TOK * H_DIM * 2;      //  33,554,432
  const size_t szP  = (size_t)CT_NUM * N_TOK * 4;     //   4,096,000
  const size_t szT  = (size_t)N_TOK * 4;
  const size_t needFull = szWb + szXb + 2 * szP + 3 * szT;

  bool full = (ws_size >= needFull);
  unsigned short* Wb = nullptr;
  unsigned short* Xb = nullptr;
  size_t off = 0;
  if (full) { Wb = (unsigned short*)ws; Xb = (unsigned short*)(ws + szWb); off = szWb + szXb; }
  float* pmax   = (float*)(ws + off); off += szP;
  float* psum   = (float*)(ws + off); off += szP;
  float* tl     = (float*)(ws + off); off += szT;
  float* lossb  = (float*)(ws + off); off += szT;
  float* validb = (float*)(ws + off);

  if (full) {
    cast_f32_to_bf16<<<4096, 256, 0, stream>>>(W, Wb, (int)((size_t)V_DIM * H_DIM / 4));
    cast_f32_to_bf16<<<1024, 256, 0, stream>>>(x, Xb, (int)((size_t)N_TOK * H_DIM / 4));
    gemm_lse<0><<<CT_NUM * MT_NUM, 256, 0, stream>>>(Xb, Wb, nullptr, nullptr, pmax, psum);
  } else {
    gemm_lse<1><<<CT_NUM * MT_NUM, 256, 0, stream>>>(nullptr, nullptr, x, W, pmax, psum);
  }
  target_logit<<<N_TOK, 256, 0, stream>>>(x, W, y, tl);
  combine_rows<<<N_TOK / 256, 256, 0, stream>>>(pmax, psum, tl, y, lossb, validb);
  finalize_loss<<<1, 256, 0, stream>>>(lossb, validb, out);
}

// Round 3
// 1136.116 us; speedup vs baseline: 1.6198x; 1.6198x over previous
//
#include <hip/hip_runtime.h>
#include <stdint.h>
#include <math.h>

#define N_TOK 4096
#define H_DIM 4096
#define V_DIM 32000

// ---- 8-phase 256x256 GEMM geometry ----
#define BM2 256
#define BN2 256
#define BK2 64
#define NKT (H_DIM / BK2)     // 64 K-tiles
#define CT2 (V_DIM / BN2)     // 125 column tiles
#define MT2 (N_TOK / BM2)     // 16 row tiles

// ---- legacy 128x128 fallback geometry (MODE-1, small-ws) ----
#define BM 128
#define BN 128
#define BK 64
#define CT_NUM (V_DIM / BN)   // 250
#define MT_NUM (N_TOK / BM)   // 32

typedef __attribute__((ext_vector_type(8))) short short8;
typedef __attribute__((ext_vector_type(4))) float f32x4;

__device__ __forceinline__ unsigned short f2bf(float x) {
  union { float f; unsigned int u; } v; v.f = x;
  unsigned int r = v.u + 0x7fffu + ((v.u >> 16) & 1u);
  return (unsigned short)(r >> 16);
}

__device__ __forceinline__ void async16(const unsigned short* g, void* lds) {
  __builtin_amdgcn_global_load_lds(
      (const __attribute__((address_space(1))) void*)g,
      (__attribute__((address_space(3))) void*)lds, 16, 0, 0);
}

__global__ __launch_bounds__(256) void cast_f32_to_bf16(
    const float* __restrict__ in, unsigned short* __restrict__ out, int n4) {
  int stride = gridDim.x * blockDim.x;
  for (int idx = blockIdx.x * blockDim.x + threadIdx.x; idx < n4; idx += stride) {
    float4 v = ((const float4*)in)[idx];
    ushort4 o;
    o.x = f2bf(v.x); o.y = f2bf(v.y); o.z = f2bf(v.z); o.w = f2bf(v.w);
    ((ushort4*)out)[idx] = o;
  }
}

// ---------------- 8-phase 256^2 fused GEMM + per-tile LSE partials ----------
// LDS: buf p at p*65536; A region +0 (256 rows x 128B), B region +32768.
// Swizzle: logical 16B-slot ls stored at physical slot ls ^ (row&7).
// global_load_lds writes linearly -> source address carries the inverse
// permutation (rule #21: linear dest + inverse-swz source + swz on read).

__device__ __forceinline__ void stage_half(const unsigned short* __restrict__ src,
    int row0, int kt, char* region, int tid) {
  const int ls = (tid & 7) ^ ((tid >> 3) & 7);
#pragma unroll
  for (int j = 0; j < 2; j++) {
    int r = j * 64 + (tid >> 3);
    const unsigned short* g = src + (size_t)(row0 + r) * H_DIM + kt * 64 + ls * 8;
    async16(g, region + j * 8192 + (tid >> 6) * 1024);
  }
}

template<int P>
__device__ __forceinline__ void phase_group(char* lds,
    const unsigned short* __restrict__ Xb, const unsigned short* __restrict__ Wb,
    int mbase, int cbase, int ktA, int ktB, int tid,
    int aRowByte, int bRowByte, int c0, int c1, f32x4 (&acc)[8][4]) {
  const char* aB = lds + P * 65536;
  const char* bB = aB + 32768;
  short8 breg[4][2];
#pragma unroll
  for (int q = 0; q < 4; q++) {
    if (q == 0) {
#pragma unroll
      for (int nf = 0; nf < 4; nf++) {
        breg[nf][0] = *(const short8*)(bB + bRowByte + nf * 2048 + c0);
        breg[nf][1] = *(const short8*)(bB + bRowByte + nf * 2048 + c1);
      }
    }
    short8 a00 = *(const short8*)(aB + aRowByte + (2 * q) * 2048 + c0);
    short8 a01 = *(const short8*)(aB + aRowByte + (2 * q) * 2048 + c1);
    short8 a10 = *(const short8*)(aB + aRowByte + (2 * q + 1) * 2048 + c0);
    short8 a11 = *(const short8*)(aB + aRowByte + (2 * q + 1) * 2048 + c1);
    // stage one half-tile (region legality: see schedule proof in analysis)
    if (q == 0)      stage_half(Xb, mbase,       ktA, lds + (P ^ 1) * 65536,         tid);
    else if (q == 1) stage_half(Xb, mbase + 128, ktA, lds + (P ^ 1) * 65536 + 16384, tid);
    else if (q == 2) stage_half(Wb, cbase,       ktB, lds + P * 65536 + 32768,       tid);
    else {           stage_half(Wb, cbase + 128, ktB, lds + P * 65536 + 49152,       tid);
                     asm volatile("s_waitcnt vmcnt(4)" ::: "memory"); }
    asm volatile("s_barrier" ::: "memory");
    asm volatile("s_waitcnt lgkmcnt(0)" ::: "memory");
    __builtin_amdgcn_sched_barrier(0);
    __builtin_amdgcn_s_setprio(1);
#pragma unroll
    for (int dm = 0; dm < 2; dm++) {
#pragma unroll
      for (int nf = 0; nf < 4; nf++) {
        acc[2 * q + dm][nf] = __builtin_amdgcn_mfma_f32_16x16x32_bf16(
            dm ? a10 : a00, breg[nf][0], acc[2 * q + dm][nf], 0, 0, 0);
        acc[2 * q + dm][nf] = __builtin_amdgcn_mfma_f32_16x16x32_bf16(
            dm ? a11 : a01, breg[nf][1], acc[2 * q + dm][nf], 0, 0, 0);
      }
    }
    __builtin_amdgcn_s_setprio(0);
    __builtin_amdgcn_sched_barrier(0);
    asm volatile("s_barrier" ::: "memory");
  }
}

__global__ __launch_bounds__(512, 2) void gemm_lse8(
    const unsigned short* __restrict__ Xb, const unsigned short* __restrict__ Wb,
    float* __restrict__ pmax, float* __restrict__ psum) {
  extern __shared__ char lds[];
  const int tid = threadIdx.x;
  const int lane = tid & 63;
  const int wid = tid >> 6;
  const int wm = wid >> 2, wn = wid & 3;

  // XCD-aware swizzle (2000 % 8 == 0 -> simple form bijective), mt-fastest.
  int logical = (blockIdx.x & 7) * (CT2 * MT2 / 8) + (blockIdx.x >> 3);
  const int ct = logical / MT2, mt = logical - ct * MT2;
  const int mbase = mt * BM2, cbase = ct * BN2;

  const int g4 = (lane >> 4) << 4;
  const int sx = (lane & 7) << 4;          // row&7 == lane&7 for all frag rows
  const int c0 = g4 ^ sx;                  // kk=0 column byte (swizzled)
  const int c1 = (64 + g4) ^ sx;           // kk=1
  const int aRowByte = ((wm << 7) + (lane & 15)) * 128;
  const int bRowByte = ((wn << 6) + (lane & 15)) * 128;

  f32x4 acc[8][4];
#pragma unroll
  for (int i = 0; i < 8; i++)
#pragma unroll
    for (int j = 0; j < 4; j++) { f32x4 z = {0.f, 0.f, 0.f, 0.f}; acc[i][j] = z; }

  // Prologue: K-tile 0 fully + K-tile 1 B-halves; keep 1B in flight.
  stage_half(Xb, mbase,       0, lds + 0,             tid);
  stage_half(Xb, mbase + 128, 0, lds + 16384,         tid);
  stage_half(Wb, cbase,       0, lds + 32768,         tid);
  stage_half(Wb, cbase + 128, 0, lds + 49152,         tid);
  stage_half(Wb, cbase,       1, lds + 65536 + 32768, tid);
  stage_half(Wb, cbase + 128, 1, lds + 65536 + 49152, tid);
  asm volatile("s_waitcnt vmcnt(4)" ::: "memory");
  asm volatile("s_barrier" ::: "memory");

#pragma unroll 1
  for (int i = 0; i < NKT / 2; i++) {
    int ktA0 = 2 * i + 1;                                   // always <= 63
    int ktB0 = (2 * i + 2 < NKT) ? 2 * i + 2 : NKT - 1;     // clamped tail
    int ktB1 = (2 * i + 3 < NKT) ? 2 * i + 3 : NKT - 1;
    phase_group<0>(lds, Xb, Wb, mbase, cbase, ktA0, ktB0, tid,
                   aRowByte, bRowByte, c0, c1, acc);
    phase_group<1>(lds, Xb, Wb, mbase, cbase, ktB0, ktB1, tid,
                   aRowByte, bRowByte, c0, c1, acc);
  }

  asm volatile("s_waitcnt vmcnt(0)" ::: "memory");
  __syncthreads();

  // Per-row (max, sum-exp) over this block's 256 vocab columns.
  float2* red = (float2*)lds;   // [256 rows][4 wn]
#pragma unroll
  for (int mf = 0; mf < 8; mf++) {
#pragma unroll
    for (int qq = 0; qq < 4; qq++) {
      float v0 = acc[mf][0][qq], v1 = acc[mf][1][qq];
      float v2 = acc[mf][2][qq], v3 = acc[mf][3][qq];
      float mx = fmaxf(fmaxf(v0, v1), fmaxf(v2, v3));
#pragma unroll
      for (int d = 1; d < 16; d <<= 1) mx = fmaxf(mx, __shfl_xor(mx, d));
      float se = __expf(v0 - mx) + __expf(v1 - mx) + __expf(v2 - mx) + __expf(v3 - mx);
#pragma unroll
      for (int d = 1; d < 16; d <<= 1) se += __shfl_xor(se, d);
      if ((lane & 15) == 0) {
        int row = (wm << 7) + mf * 16 + ((lane >> 4) << 2) + qq;
        float2 v; v.x = mx; v.y = se;
        red[row * 4 + wn] = v;
      }
    }
  }
  __syncthreads();
  if (tid < 256) {
    float M = -INFINITY, S = 0.f;
#pragma unroll
    for (int w = 0; w < 4; w++) {
      float2 r = red[tid * 4 + w];
      float Mn = fmaxf(M, r.x);
      S = S * __expf(M - Mn) + r.y * __expf(r.x - Mn);
      M = Mn;
    }
    size_t o = (size_t)ct * N_TOK + mbase + tid;
    pmax[o] = M;
    psum[o] = S;
  }
}

// ---------------- legacy 128^2 kernel, MODE-1 fallback (fp32 inputs) --------
__global__ __launch_bounds__(256) void gemm_lse_small(
    const float* __restrict__ Xf, const float* __restrict__ Wf,
    float* __restrict__ pmax, float* __restrict__ psum) {
  __shared__ unsigned short As[BM * BK];
  __shared__ unsigned short Bs[BN * BK];
  const int ct = blockIdx.x / MT_NUM;
  const int mt = blockIdx.x % MT_NUM;
  const int mbase = mt * BM, cbase = ct * BN;
  const int tid = threadIdx.x;
  const int lane = tid & 63;
  const int wid = tid >> 6;
  const int wr = wid >> 1, wc = wid & 1;
  f32x4 acc[4][4];
#pragma unroll
  for (int i = 0; i < 4; i++)
#pragma unroll
    for (int j = 0; j < 4; j++) { f32x4 z = {0.f, 0.f, 0.f, 0.f}; acc[i][j] = z; }
  for (int ks = 0; ks < H_DIM / BK; ks++) {
    const int k0 = ks * BK;
#pragma unroll
    for (int r = 0; r < 4; r++) {
      int o = r * 4096 + wid * 1024 + lane * 16;
      int row = o >> 7;
      int kc = (o & 127) >> 1;
      const float* xs = Xf + (size_t)(mbase + row) * H_DIM + k0 + kc;
      const float* wv = Wf + (size_t)(cbase + row) * H_DIM + k0 + kc;
      float4 x0 = *(const float4*)xs, x1 = *(const float4*)(xs + 4);
      float4 w0 = *(const float4*)wv, w1 = *(const float4*)(wv + 4);
      short8 xa, wa;
      xa[0] = f2bf(x0.x); xa[1] = f2bf(x0.y); xa[2] = f2bf(x0.z); xa[3] = f2bf(x0.w);
      xa[4] = f2bf(x1.x); xa[5] = f2bf(x1.y); xa[6] = f2bf(x1.z); xa[7] = f2bf(x1.w);
      wa[0] = f2bf(w0.x); wa[1] = f2bf(w0.y); wa[2] = f2bf(w0.z); wa[3] = f2bf(w0.w);
      wa[4] = f2bf(w1.x); wa[5] = f2bf(w1.y); wa[6] = f2bf(w1.z); wa[7] = f2bf(w1.w);
      *(short8*)((char*)As + o) = xa;
      *(short8*)((char*)Bs + o) = wa;
    }
    __syncthreads();
#pragma unroll
    for (int kk = 0; kk < 2; kk++) {
      short8 a[4], b[4];
#pragma unroll
      for (int m = 0; m < 4; m++)
        a[m] = *(const short8*)((const char*)As +
                (wr * 64 + m * 16 + (lane & 15)) * 128 + kk * 64 + (lane >> 4) * 16);
#pragma unroll
      for (int n = 0; n < 4; n++)
        b[n] = *(const short8*)((const char*)Bs +
                (wc * 64 + n * 16 + (lane & 15)) * 128 + kk * 64 + (lane >> 4) * 16);
#pragma unroll
      for (int m = 0; m < 4; m++)
#pragma unroll
        for (int n = 0; n < 4; n++)
          acc[m][n] = __builtin_amdgcn_mfma_f32_16x16x32_bf16(a[m], b[n], acc[m][n], 0, 0, 0);
    }
    __syncthreads();
  }
  float* red = (float*)As;
  const int g = lane >> 4;
#pragma unroll
  for (int m = 0; m < 4; m++) {
#pragma unroll
    for (int q = 0; q < 4; q++) {
      float v0 = acc[m][0][q], v1 = acc[m][1][q], v2 = acc[m][2][q], v3 = acc[m][3][q];
      float mx = fmaxf(fmaxf(v0, v1), fmaxf(v2, v3));
#pragma unroll
      for (int d = 1; d < 16; d <<= 1) mx = fmaxf(mx, __shfl_xor(mx, d));
      float se = __expf(v0 - mx) + __expf(v1 - mx) + __expf(v2 - mx) + __expf(v3 - mx);
#pragma unroll
      for (int d = 1; d < 16; d <<= 1) se += __shfl_xor(se, d);
      if ((lane & 15) == 0) {
        int row = wr * 64 + m * 16 + g * 4 + q;
        red[row * 4 + wc * 2 + 0] = mx;
        red[row * 4 + wc * 2 + 1] = se;
      }
    }
  }
  __syncthreads();
  if (tid < BM) {
    float m0 = red[tid * 4 + 0], s0 = red[tid * 4 + 1];
    float m1 = red[tid * 4 + 2], s1 = red[tid * 4 + 3];
    float M = fmaxf(m0, m1);
    float S = s0 * __expf(m0 - M) + s1 * __expf(m1 - M);
    size_t o = (size_t)ct * N_TOK + mbase + tid;
    pmax[o] = M;
    psum[o] = S;
  }
}

// ---------------- exact fp32 target logit + reduction kernels ---------------
__global__ __launch_bounds__(256) void target_logit(
    const float* __restrict__ X, const float* __restrict__ W,
    const int* __restrict__ y, float* __restrict__ tl) {
  __shared__ float red[4];
  int row = blockIdx.x;
  int lab = y[row];
  float s = 0.f;
  if (lab >= 0 && lab < V_DIM) {
    const float4* xr = (const float4*)(X + (size_t)row * H_DIM);
    const float4* wr = (const float4*)(W + (size_t)lab * H_DIM);
    for (int i = threadIdx.x; i < H_DIM / 4; i += 256) {
      float4 a = xr[i], b = wr[i];
      s += a.x * b.x + a.y * b.y + a.z * b.z + a.w * b.w;
    }
  }
#pragma unroll
  for (int o = 32; o > 0; o >>= 1) s += __shfl_down(s, o);
  if ((threadIdx.x & 63) == 0) red[threadIdx.x >> 6] = s;
  __syncthreads();
  if (threadIdx.x == 0) tl[row] = red[0] + red[1] + red[2] + red[3];
}

__global__ __launch_bounds__(256) void combine_rows(
    const float* __restrict__ pmax, const float* __restrict__ psum,
    const float* __restrict__ tl, const int* __restrict__ y,
    float* __restrict__ lossb, float* __restrict__ validb, int n_ct) {
  int row = blockIdx.x * 256 + threadIdx.x;
  if (row >= N_TOK) return;
  float M = -INFINITY, S = 0.f;
  for (int ct = 0; ct < n_ct; ct++) {
    float m = pmax[(size_t)ct * N_TOK + row];
    float s = psum[(size_t)ct * N_TOK + row];
    float Mn = fmaxf(M, m);
    S = S * __expf(M - Mn) + s * __expf(m - Mn);
    M = Mn;
  }
  bool valid = (y[row] != -100);
  lossb[row] = valid ? (M + __logf(S) - tl[row]) : 0.f;
  validb[row] = valid ? 1.f : 0.f;
}

__global__ __launch_bounds__(256) void finalize_loss(
    const float* __restrict__ lossb, const float* __restrict__ validb,
    float* __restrict__ out) {
  __shared__ float rs[4], rc[4];
  float s = 0.f, c = 0.f;
  for (int i = threadIdx.x; i < N_TOK; i += 256) { s += lossb[i]; c += validb[i]; }
#pragma unroll
  for (int o = 32; o > 0; o >>= 1) { s += __shfl_down(s, o); c += __shfl_down(c, o); }
  if ((threadIdx.x & 63) == 0) { rs[threadIdx.x >> 6] = s; rc[threadIdx.x >> 6] = c; }
  __syncthreads();
  if (threadIdx.x == 0) {
    float S = rs[0] + rs[1] + rs[2] + rs[3];
    float C = rc[0] + rc[1] + rc[2] + rc[3];
    out[0] = S / fmaxf(C, 1.f);
  }
}

extern "C" void kernel_launch(void* const* d_in, const int* in_sizes, int n_in,
                              void* d_out, int out_size, void* d_ws, size_t ws_size,
                              hipStream_t stream) {
  const float* x = (const float*)d_in[0];
  const int* y = (const int*)d_in[1];
  const float* W = (const float*)d_in[2];
  float* out = (float*)d_out;
  char* ws = (char*)d_ws;

  const size_t szWb = (size_t)V_DIM * H_DIM * 2;
  const size_t szXb = (size_t)N_TOK * H_DIM * 2;
  const size_t szP  = (size_t)CT_NUM * N_TOK * 4;   // sized for the 250-tile fallback
  const size_t szT  = (size_t)N_TOK * 4;
  const size_t needFull = szWb + szXb + 2 * szP + 3 * szT;

  bool full = (ws_size >= needFull);
  unsigned short* Wb = nullptr;
  unsigned short* Xb = nullptr;
  size_t off = 0;
  if (full) { Wb = (unsigned short*)ws; Xb = (unsigned short*)(ws + szWb); off = szWb + szXb; }
  float* pmax   = (float*)(ws + off); off += szP;
  float* psum   = (float*)(ws + off); off += szP;
  float* tl     = (float*)(ws + off); off += szT;
  float* lossb  = (float*)(ws + off); off += szT;
  float* validb = (float*)(ws + off);

  if (full) {
    cast_f32_to_bf16<<<4096, 256, 0, stream>>>(W, Wb, (int)((size_t)V_DIM * H_DIM / 4));
    cast_f32_to_bf16<<<1024, 256, 0, stream>>>(x, Xb, (int)((size_t)N_TOK * H_DIM / 4));
    (void)hipFuncSetAttribute((const void*)gemm_lse8,
        hipFuncAttributeMaxDynamicSharedMemorySize, 131072);
    gemm_lse8<<<CT2 * MT2, 512, 131072, stream>>>(Xb, Wb, pmax, psum);
    target_logit<<<N_TOK, 256, 0, stream>>>(x, W, y, tl);
    combine_rows<<<N_TOK / 256, 256, 0, stream>>>(pmax, psum, tl, y, lossb, validb, CT2);
  } else {
    gemm_lse_small<<<CT_NUM * MT_NUM, 256, 0, stream>>>(x, W, pmax, psum);
    target_logit<<<N_TOK, 256, 0, stream>>>(x, W, y, tl);
    combine_rows<<<N_TOK / 256, 256, 0, stream>>>(pmax, psum, tl, y, lossb, validb, CT_NUM);
  }
  finalize_loss<<<1, 256, 0, stream>>>(lossb, validb, out);
}